// Round 3
// baseline (51291.248 us; speedup 1.0000x reference)
//
#include <hip/hip_runtime.h>
#include <hip/hip_bf16.h>

// Problem constants (BinaryClassifyModel: L=6, B=8, S=2048, H=768, V=32000)
// All model inputs are float32 (per reference); internal activations bf16.
#define Bn 8
#define Sn 2048
#define Hn 768
#define FFn 3072
#define Ln 6
#define BSn (Bn * Sn)       // 16384 tokens
#define LN_EPS 1e-5f

typedef __hip_bfloat16 bf16;

__device__ __forceinline__ float b2f(bf16 v) { return __bfloat162float(v); }
__device__ __forceinline__ void stc(float* p, float v) { *p = v; }
__device__ __forceinline__ void stc(bf16* p, float v) { *p = __float2bfloat16(v); }

// ---------------------------------------------------------------------------
// Embedding: x[b,s,:] = tok_emb[ids[b,s],:] + pos_emb[s,:]   (f32 in, f32 out)
// ---------------------------------------------------------------------------
__global__ void __launch_bounds__(256) embed_kernel(
    const int* __restrict__ ids, const float* __restrict__ tok,
    const float* __restrict__ pos, float* __restrict__ x) {
  long t = blockIdx.x;              // token index 0..BS-1
  int s = (int)(t & (Sn - 1));
  long id = ids[t];
  const float* tr = tok + id * Hn;
  const float* pr = pos + (long)s * Hn;
  float* xr = x + t * Hn;
  for (int d = threadIdx.x; d < Hn; d += 256)
    xr[d] = tr[d] + pr[d];
}

// ---------------------------------------------------------------------------
// LayerNorm: one 256-thread block per token (H=768 -> 3 elems/thread)
// x: f32 in, out: bf16
// ---------------------------------------------------------------------------
__global__ void __launch_bounds__(256) ln_kernel(
    const float* __restrict__ x, const float* __restrict__ g,
    const float* __restrict__ b, bf16* __restrict__ out) {
  long token = blockIdx.x;
  const float* xr = x + token * Hn;
  bf16* orow = out + token * Hn;
  int tid = threadIdx.x;

  float vals[3];
  float s1 = 0.f;
#pragma unroll
  for (int i = 0; i < 3; i++) {
    vals[i] = xr[tid + 256 * i];
    s1 += vals[i];
  }
  __shared__ float sb[4];
  __shared__ float stat[2];
#pragma unroll
  for (int off = 32; off > 0; off >>= 1) s1 += __shfl_down(s1, off, 64);
  if ((tid & 63) == 0) sb[tid >> 6] = s1;
  __syncthreads();
  if (tid == 0) stat[0] = (sb[0] + sb[1] + sb[2] + sb[3]) * (1.0f / Hn);
  __syncthreads();
  float mean = stat[0];

  float s2 = 0.f;
#pragma unroll
  for (int i = 0; i < 3; i++) {
    float d = vals[i] - mean;
    s2 += d * d;
  }
#pragma unroll
  for (int off = 32; off > 0; off >>= 1) s2 += __shfl_down(s2, off, 64);
  if ((tid & 63) == 0) sb[tid >> 6] = s2;
  __syncthreads();
  if (tid == 0)
    stat[1] = rsqrtf((sb[0] + sb[1] + sb[2] + sb[3]) * (1.0f / Hn) + LN_EPS);
  __syncthreads();
  float inv = stat[1];

#pragma unroll
  for (int i = 0; i < 3; i++) {
    int d = tid + 256 * i;
    stc(orow + d, (vals[i] - mean) * inv * g[d] + b[d]);
  }
}

// ---------------------------------------------------------------------------
// GEMM: C[M,N] = epilogue(A[M,K] @ W[K,N] + bias[N] (+ res[M,N]))
//   A: bf16 (internal activations);  W, bias: f32 (model weights);
//   res: f32;  C: CT (bf16 or f32)
//   EPI: 0 = bias only, 1 = bias + residual, 2 = gelu(bias)
//   64x64 tile, BK=16, 256 threads, 4x4 per-thread register block.
//   All M,N divisible by 64, K divisible by 16 (no bounds checks).
// ---------------------------------------------------------------------------
template <int EPI, typename CT>
__global__ void __launch_bounds__(256) gemm_kernel(
    const bf16* __restrict__ A, const float* __restrict__ W,
    const float* __restrict__ bias, const float* __restrict__ res,
    CT* __restrict__ C, int M, int N, int K) {
  __shared__ float As[64][17];   // [m][k], padded to dodge bank conflicts
  __shared__ float Bs[16][64];   // [k][n]
  int tid = threadIdx.x;
  int tx = tid & 15;             // 0..15 -> 4 cols each
  int ty = tid >> 4;             // 0..15 -> 4 rows each
  long rowBase = (long)blockIdx.y * 64;
  int colBase = blockIdx.x * 64;

  float acc[4][4] = {};

  for (int kt = 0; kt < K; kt += 16) {
    // Load A tile 64x16 (each thread 4 elems), bf16 -> f32
#pragma unroll
    for (int i = 0; i < 4; i++) {
      int e = tid + i * 256;
      int kl = e & 15;
      int ml = e >> 4;
      As[ml][kl] = b2f(A[(rowBase + ml) * K + kt + kl]);
    }
    // Load W tile 16x64 (coalesced along N), f32
#pragma unroll
    for (int i = 0; i < 4; i++) {
      int e = tid + i * 256;
      int nl = e & 63;
      int kl = e >> 6;
      Bs[kl][nl] = W[(long)(kt + kl) * N + colBase + nl];
    }
    __syncthreads();
#pragma unroll
    for (int kk = 0; kk < 16; kk++) {
      float a[4], bb[4];
#pragma unroll
      for (int i = 0; i < 4; i++) a[i] = As[ty * 4 + i][kk];
#pragma unroll
      for (int j = 0; j < 4; j++) bb[j] = Bs[kk][tx * 4 + j];
#pragma unroll
      for (int i = 0; i < 4; i++)
#pragma unroll
        for (int j = 0; j < 4; j++) acc[i][j] += a[i] * bb[j];
    }
    __syncthreads();
  }

#pragma unroll
  for (int i = 0; i < 4; i++) {
    long row = rowBase + ty * 4 + i;
#pragma unroll
    for (int j = 0; j < 4; j++) {
      int col = colBase + tx * 4 + j;
      float v = acc[i][j] + bias[col];
      if (EPI == 1) v += res[row * N + col];
      if (EPI == 2) v = 0.5f * v * (1.0f + erff(v * 0.70710678118654752f));
      stc(C + row * N + col, v);
    }
  }
}

// ---------------------------------------------------------------------------
// Single-head causal attention, one block per (query, batch). q,k,v,o: bf16.
// Scores row kept in LDS (<= S=2048 floats). Pad mask from attention_mask.
// ---------------------------------------------------------------------------
__global__ void __launch_bounds__(256) attn_kernel(
    const bf16* __restrict__ q, const bf16* __restrict__ k,
    const bf16* __restrict__ v, const int* __restrict__ mask,
    bf16* __restrict__ o) {
  int qi = blockIdx.x;
  int b = blockIdx.y;
  int tid = threadIdx.x;
  const float scale = 0.03608439182435161f;  // 1/sqrt(768)

  __shared__ float qs[Hn];
  __shared__ float sc[Sn];
  __shared__ float sb[4];
  __shared__ float stat;

  long base = (long)b * Sn * Hn;
  const bf16* qrow = q + base + (long)qi * Hn;
  for (int d = tid; d < Hn; d += 256) qs[d] = b2f(qrow[d]) * scale;
  __syncthreads();

  int nk = qi + 1;  // causal: keys 0..qi inclusive
  float lmax = -1e30f;
  for (int kk = tid; kk < nk; kk += 256) {
    const bf16* kr = k + base + (long)kk * Hn;
    float dot = 0.f;
    for (int d = 0; d < Hn; d++) dot += qs[d] * b2f(kr[d]);
    if (mask[b * Sn + kk] == 0) dot = -1e30f;
    sc[kk] = dot;
    lmax = fmaxf(lmax, dot);
  }
#pragma unroll
  for (int off = 32; off > 0; off >>= 1)
    lmax = fmaxf(lmax, __shfl_down(lmax, off, 64));
  if ((tid & 63) == 0) sb[tid >> 6] = lmax;
  __syncthreads();
  if (tid == 0) stat = fmaxf(fmaxf(sb[0], sb[1]), fmaxf(sb[2], sb[3]));
  __syncthreads();
  float gmax = stat;

  float lsum = 0.f;
  for (int kk = tid; kk < nk; kk += 256) {
    float e = __expf(sc[kk] - gmax);
    sc[kk] = e;
    lsum += e;
  }
#pragma unroll
  for (int off = 32; off > 0; off >>= 1) lsum += __shfl_down(lsum, off, 64);
  if ((tid & 63) == 0) sb[tid >> 6] = lsum;
  __syncthreads();
  if (tid == 0) stat = sb[0] + sb[1] + sb[2] + sb[3];
  __syncthreads();  // also publishes all sc[] exp writes to every thread
  float inv = 1.0f / stat;

  // P @ V: thread owns dims tid, tid+256, tid+512 (coalesced v reads per kk)
  float a0 = 0.f, a1 = 0.f, a2 = 0.f;
  const bf16* vbp = v + base;
  int d0 = tid, d1 = tid + 256, d2 = tid + 512;
  for (int kk = 0; kk < nk; kk++) {
    float p = sc[kk];
    const bf16* vr = vbp + (long)kk * Hn;
    a0 += p * b2f(vr[d0]);
    a1 += p * b2f(vr[d1]);
    a2 += p * b2f(vr[d2]);
  }
  bf16* orow = o + base + (long)qi * Hn;
  stc(orow + d0, a0 * inv);
  stc(orow + d1, a1 * inv);
  stc(orow + d2, a2 * inv);
}

// ---------------------------------------------------------------------------
// Classifier head: last non-pad token per batch row, dot with cls_W. out: f32
// ---------------------------------------------------------------------------
__global__ void __launch_bounds__(256) cls_kernel(
    const bf16* __restrict__ h, const int* __restrict__ mask,
    const float* __restrict__ clsW, const float* __restrict__ clsb,
    float* __restrict__ out) {
  int b = blockIdx.x;
  int tid = threadIdx.x;
  __shared__ float sb[4];
  __shared__ int ib[4];
  __shared__ int lastsh;

  int ls = 0;
  for (int s = tid; s < Sn; s += 256) ls += mask[b * Sn + s];
#pragma unroll
  for (int off = 32; off > 0; off >>= 1) ls += __shfl_down(ls, off, 64);
  if ((tid & 63) == 0) ib[tid >> 6] = ls;
  __syncthreads();
  if (tid == 0) lastsh = ib[0] + ib[1] + ib[2] + ib[3] - 1;
  __syncthreads();
  int last = lastsh;

  const bf16* row = h + ((long)b * Sn + last) * Hn;
  float acc = 0.f;
  for (int d = tid; d < Hn; d += 256) acc += b2f(row[d]) * clsW[d];
#pragma unroll
  for (int off = 32; off > 0; off >>= 1) acc += __shfl_down(acc, off, 64);
  if ((tid & 63) == 0) sb[tid >> 6] = acc;
  __syncthreads();
  if (tid == 0) out[b] = sb[0] + sb[1] + sb[2] + sb[3] + clsb[0];
}

// ---------------------------------------------------------------------------
// Orchestration
// ---------------------------------------------------------------------------
extern "C" void kernel_launch(void* const* d_in, const int* in_sizes, int n_in,
                              void* d_out, int out_size, void* d_ws,
                              size_t ws_size, hipStream_t stream) {
  const int* ids     = (const int*)d_in[0];
  const int* mask    = (const int*)d_in[1];
  const float* tok   = (const float*)d_in[2];
  const float* pos   = (const float*)d_in[3];
  const float* Wq    = (const float*)d_in[4];
  const float* bq    = (const float*)d_in[5];
  const float* Wk    = (const float*)d_in[6];
  const float* bk    = (const float*)d_in[7];
  const float* Wv    = (const float*)d_in[8];
  const float* bv    = (const float*)d_in[9];
  const float* Wo    = (const float*)d_in[10];
  const float* bo    = (const float*)d_in[11];
  const float* ln1g  = (const float*)d_in[12];
  const float* ln1b  = (const float*)d_in[13];
  const float* ln2g  = (const float*)d_in[14];
  const float* ln2b  = (const float*)d_in[15];
  const float* W1    = (const float*)d_in[16];
  const float* b1    = (const float*)d_in[17];
  const float* W2    = (const float*)d_in[18];
  const float* b2    = (const float*)d_in[19];
  const float* flng  = (const float*)d_in[20];
  const float* flnb  = (const float*)d_in[21];
  const float* clsW  = (const float*)d_in[22];
  const float* clsb  = (const float*)d_in[23];

  // Workspace layout (~176 MB total):
  //   x  : BS*H f32   (persistent hidden state)         50.3 MB
  //   h  : BS*H bf16  (LN output / attention output)    25.2 MB
  //   cb : BS*FF bf16 (q,k,v during attention; FFN mid) 100.7 MB
  float* x = (float*)d_ws;
  bf16* h  = (bf16*)(x + (size_t)BSn * Hn);
  bf16* cb = h + (size_t)BSn * Hn;
  bf16* qb = cb;
  bf16* kb = cb + (size_t)BSn * Hn;
  bf16* vb = cb + 2 * (size_t)BSn * Hn;

  const int M = BSn;
  dim3 blk(256);
  dim3 gridH(Hn / 64, M / 64);    // N=768
  dim3 gridF(FFn / 64, M / 64);   // N=3072
  dim3 gridA(Sn, Bn);

  embed_kernel<<<BSn, blk, 0, stream>>>(ids, tok, pos, x);

  for (int l = 0; l < Ln; l++) {
    const float* Wq_l = Wq + (size_t)l * Hn * Hn;
    const float* Wk_l = Wk + (size_t)l * Hn * Hn;
    const float* Wv_l = Wv + (size_t)l * Hn * Hn;
    const float* Wo_l = Wo + (size_t)l * Hn * Hn;
    const float* W1_l = W1 + (size_t)l * Hn * FFn;
    const float* W2_l = W2 + (size_t)l * FFn * Hn;

    // --- attention block ---
    ln_kernel<<<BSn, blk, 0, stream>>>(x, ln1g + l * Hn, ln1b + l * Hn, h);
    gemm_kernel<0, bf16><<<gridH, blk, 0, stream>>>(h, Wq_l, bq + l * Hn,
                                                    nullptr, qb, M, Hn, Hn);
    gemm_kernel<0, bf16><<<gridH, blk, 0, stream>>>(h, Wk_l, bk + l * Hn,
                                                    nullptr, kb, M, Hn, Hn);
    gemm_kernel<0, bf16><<<gridH, blk, 0, stream>>>(h, Wv_l, bv + l * Hn,
                                                    nullptr, vb, M, Hn, Hn);
    attn_kernel<<<gridA, blk, 0, stream>>>(qb, kb, vb, mask, h);
    gemm_kernel<1, float><<<gridH, blk, 0, stream>>>(h, Wo_l, bo + l * Hn, x,
                                                     x, M, Hn, Hn);

    // --- FFN block ---
    ln_kernel<<<BSn, blk, 0, stream>>>(x, ln2g + l * Hn, ln2b + l * Hn, h);
    gemm_kernel<2, bf16><<<gridF, blk, 0, stream>>>(h, W1_l, b1 + l * FFn,
                                                    nullptr, cb, M, FFn, Hn);
    gemm_kernel<1, float><<<gridH, blk, 0, stream>>>(cb, W2_l, b2 + l * Hn, x,
                                                     x, M, Hn, FFn);
  }

  ln_kernel<<<BSn, blk, 0, stream>>>(x, flng, flnb, h);
  cls_kernel<<<Bn, blk, 0, stream>>>(h, mask, clsW, clsb, (float*)d_out);
}

// Round 4
// 29057.660 us; speedup vs baseline: 1.7652x; 1.7652x over previous
//
#include <hip/hip_runtime.h>
#include <hip/hip_bf16.h>

// Problem constants (BinaryClassifyModel: L=6, B=8, S=2048, H=768, V=32000)
// All model inputs are float32 (per reference); internal activations bf16.
#define Bn 8
#define Sn 2048
#define Hn 768
#define FFn 3072
#define Ln 6
#define BSn (Bn * Sn)       // 16384 tokens
#define CQ 512              // query chunk for attention scores buffer
#define LN_EPS 1e-5f

typedef __hip_bfloat16 bf16;

__device__ __forceinline__ float b2f(bf16 v) { return __bfloat162float(v); }
__device__ __forceinline__ void stc(float* p, float v) { *p = v; }
__device__ __forceinline__ void stc(bf16* p, float v) { *p = __float2bfloat16(v); }

union Pk8 { float4 v; bf16 h[8]; };   // 8 consecutive bf16 = one 16B load

// ---------------------------------------------------------------------------
// Embedding: x[b,s,:] = tok_emb[ids[b,s],:] + pos_emb[s,:]   (f32 in, f32 out)
// ---------------------------------------------------------------------------
__global__ void __launch_bounds__(256) embed_kernel(
    const int* __restrict__ ids, const float* __restrict__ tok,
    const float* __restrict__ pos, float* __restrict__ x) {
  long t = blockIdx.x;              // token index 0..BS-1
  int s = (int)(t & (Sn - 1));
  long id = ids[t];
  const float* tr = tok + id * Hn;
  const float* pr = pos + (long)s * Hn;
  float* xr = x + t * Hn;
  for (int d = threadIdx.x; d < Hn; d += 256)
    xr[d] = tr[d] + pr[d];
}

// ---------------------------------------------------------------------------
// LayerNorm: one 256-thread block per token (H=768 -> 3 elems/thread)
// x: f32 in, out: bf16
// ---------------------------------------------------------------------------
__global__ void __launch_bounds__(256) ln_kernel(
    const float* __restrict__ x, const float* __restrict__ g,
    const float* __restrict__ b, bf16* __restrict__ out) {
  long token = blockIdx.x;
  const float* xr = x + token * Hn;
  bf16* orow = out + token * Hn;
  int tid = threadIdx.x;

  float vals[3];
  float s1 = 0.f;
#pragma unroll
  for (int i = 0; i < 3; i++) {
    vals[i] = xr[tid + 256 * i];
    s1 += vals[i];
  }
  __shared__ float sb[4];
  __shared__ float stat[2];
#pragma unroll
  for (int off = 32; off > 0; off >>= 1) s1 += __shfl_down(s1, off, 64);
  if ((tid & 63) == 0) sb[tid >> 6] = s1;
  __syncthreads();
  if (tid == 0) stat[0] = (sb[0] + sb[1] + sb[2] + sb[3]) * (1.0f / Hn);
  __syncthreads();
  float mean = stat[0];

  float s2 = 0.f;
#pragma unroll
  for (int i = 0; i < 3; i++) {
    float d = vals[i] - mean;
    s2 += d * d;
  }
#pragma unroll
  for (int off = 32; off > 0; off >>= 1) s2 += __shfl_down(s2, off, 64);
  if ((tid & 63) == 0) sb[tid >> 6] = s2;
  __syncthreads();
  if (tid == 0)
    stat[1] = rsqrtf((sb[0] + sb[1] + sb[2] + sb[3]) * (1.0f / Hn) + LN_EPS);
  __syncthreads();
  float inv = stat[1];

#pragma unroll
  for (int i = 0; i < 3; i++) {
    int d = tid + 256 * i;
    stc(orow + d, (vals[i] - mean) * inv * g[d] + b[d]);
  }
}

// ---------------------------------------------------------------------------
// GEMM: C[M,N] = epilogue(A[M,K] @ W[K,N] + bias[N] (+ res[M,N]))
//   A: bf16 (internal activations);  W, bias: f32 (model weights);
//   res: f32;  C: CT (bf16 or f32)
//   EPI: 0 = bias only, 1 = bias + residual, 2 = gelu(bias)
// ---------------------------------------------------------------------------
template <int EPI, typename CT>
__global__ void __launch_bounds__(256) gemm_kernel(
    const bf16* __restrict__ A, const float* __restrict__ W,
    const float* __restrict__ bias, const float* __restrict__ res,
    CT* __restrict__ C, int M, int N, int K) {
  __shared__ float As[64][17];   // [m][k]
  __shared__ float Bs[16][64];   // [k][n]
  int tid = threadIdx.x;
  int tx = tid & 15;
  int ty = tid >> 4;
  long rowBase = (long)blockIdx.y * 64;
  int colBase = blockIdx.x * 64;

  float acc[4][4] = {};

  for (int kt = 0; kt < K; kt += 16) {
#pragma unroll
    for (int i = 0; i < 4; i++) {
      int e = tid + i * 256;
      int kl = e & 15;
      int ml = e >> 4;
      As[ml][kl] = b2f(A[(rowBase + ml) * K + kt + kl]);
    }
#pragma unroll
    for (int i = 0; i < 4; i++) {
      int e = tid + i * 256;
      int nl = e & 63;
      int kl = e >> 6;
      Bs[kl][nl] = W[(long)(kt + kl) * N + colBase + nl];
    }
    __syncthreads();
#pragma unroll
    for (int kk = 0; kk < 16; kk++) {
      float a[4], bb[4];
#pragma unroll
      for (int i = 0; i < 4; i++) a[i] = As[ty * 4 + i][kk];
#pragma unroll
      for (int j = 0; j < 4; j++) bb[j] = Bs[kk][tx * 4 + j];
#pragma unroll
      for (int i = 0; i < 4; i++)
#pragma unroll
        for (int j = 0; j < 4; j++) acc[i][j] += a[i] * bb[j];
    }
    __syncthreads();
  }

#pragma unroll
  for (int i = 0; i < 4; i++) {
    long row = rowBase + ty * 4 + i;
#pragma unroll
    for (int j = 0; j < 4; j++) {
      int col = colBase + tx * 4 + j;
      float v = acc[i][j] + bias[col];
      if (EPI == 1) v += res[row * N + col];
      if (EPI == 2) v = 0.5f * v * (1.0f + erff(v * 0.70710678118654752f));
      stc(C + row * N + col, v);
    }
  }
}

// ---------------------------------------------------------------------------
// QK^T: sc[b, qRel, k] = scale * dot(q[b,q0+qRel,:], k[b,k,:])
//   64x64 tile over (q,k), BK=32 over d, vectorized bf16x8 loads.
//   Tiles strictly above the causal diagonal are skipped.
// ---------------------------------------------------------------------------
__global__ void __launch_bounds__(256) qk_kernel(
    const bf16* __restrict__ q, const bf16* __restrict__ k,
    bf16* __restrict__ sc, int q0) {
  int kBase = blockIdx.x * 64;
  int qBase = q0 + blockIdx.y * 64;     // global query base
  if (kBase > qBase + 63) return;       // fully masked tile
  int b = blockIdx.z;
  long base = (long)b * Sn * Hn;
  const bf16* Q = q + base;
  const bf16* K = k + base;

  __shared__ float Qs[64][33];   // [q][d]
  __shared__ float Ks[32][65];   // [d][k] (transposed on store)
  int tid = threadIdx.x;
  int tx = tid & 15;
  int ty = tid >> 4;
  int row = tid >> 2;            // 0..63
  int dCol = (tid & 3) * 8;      // 0,8,16,24

  float acc[4][4] = {};

  for (int dt = 0; dt < Hn; dt += 32) {
    Pk8 pq, pk;
    pq.v = *reinterpret_cast<const float4*>(Q + (long)(qBase + row) * Hn + dt + dCol);
    pk.v = *reinterpret_cast<const float4*>(K + (long)(kBase + row) * Hn + dt + dCol);
#pragma unroll
    for (int i = 0; i < 8; i++) Qs[row][dCol + i] = b2f(pq.h[i]);
#pragma unroll
    for (int i = 0; i < 8; i++) Ks[dCol + i][row] = b2f(pk.h[i]);
    __syncthreads();
#pragma unroll
    for (int dd = 0; dd < 32; dd++) {
      float a[4], bb[4];
#pragma unroll
      for (int i = 0; i < 4; i++) a[i] = Qs[ty * 4 + i][dd];
#pragma unroll
      for (int j = 0; j < 4; j++) bb[j] = Ks[dd][tx * 4 + j];
#pragma unroll
      for (int i = 0; i < 4; i++)
#pragma unroll
        for (int j = 0; j < 4; j++) acc[i][j] += a[i] * bb[j];
    }
    __syncthreads();
  }

  const float scale = 0.03608439182435161f;  // 1/sqrt(768)
#pragma unroll
  for (int i = 0; i < 4; i++) {
    long qRel = qBase - q0 + ty * 4 + i;
#pragma unroll
    for (int j = 0; j < 4; j++)
      stc(sc + ((long)b * CQ + qRel) * Sn + kBase + tx * 4 + j,
          acc[i][j] * scale);
  }
}

// ---------------------------------------------------------------------------
// Softmax over one score row (block per (qRel, b)). Applies pad mask, causal
// truncation (reads k <= q only), writes P = softmax (bf16), zeros the
// slack region q < k < tile-boundary so pv_kernel can run full 64-tiles.
// ---------------------------------------------------------------------------
__global__ void __launch_bounds__(256) softmax_kernel(
    bf16* __restrict__ sc, const int* __restrict__ mask, int q0) {
  int qRel = blockIdx.x;
  int b = blockIdx.y;
  int qg = q0 + qRel;
  bf16* row = sc + ((long)b * CQ + qRel) * Sn;
  const int* mrow = mask + b * Sn;
  int tid = threadIdx.x;
  int n = qg + 1;                      // valid keys: 0..qg
  int limit = (qg & ~63) + 64;         // pv reads k in [0, limit)

  float sv[8];
  float lmax = -1e30f;
#pragma unroll
  for (int it = 0; it < 8; it++) {
    int kk = tid + it * 256;
    float s = -1e30f;
    if (kk < n) {
      s = b2f(row[kk]);
      if (mrow[kk] == 0) s = -1e30f;
    }
    sv[it] = s;
    lmax = fmaxf(lmax, s);
  }
  __shared__ float sb[4];
  __shared__ float stat;
#pragma unroll
  for (int off = 32; off > 0; off >>= 1)
    lmax = fmaxf(lmax, __shfl_down(lmax, off, 64));
  if ((tid & 63) == 0) sb[tid >> 6] = lmax;
  __syncthreads();
  if (tid == 0) stat = fmaxf(fmaxf(sb[0], sb[1]), fmaxf(sb[2], sb[3]));
  __syncthreads();
  float gmax = stat;

  float ev[8];
  float lsum = 0.f;
#pragma unroll
  for (int it = 0; it < 8; it++) {
    int kk = tid + it * 256;
    float e = 0.f;
    if (kk < n) e = __expf(sv[it] - gmax);
    ev[it] = e;
    lsum += e;
  }
#pragma unroll
  for (int off = 32; off > 0; off >>= 1) lsum += __shfl_down(lsum, off, 64);
  if ((tid & 63) == 0) sb[tid >> 6] = lsum;
  __syncthreads();
  if (tid == 0) stat = sb[0] + sb[1] + sb[2] + sb[3];
  __syncthreads();
  float inv = 1.0f / stat;

#pragma unroll
  for (int it = 0; it < 8; it++) {
    int kk = tid + it * 256;
    if (kk < n)
      stc(row + kk, ev[it] * inv);
    else if (kk < limit)
      stc(row + kk, 0.f);
  }
}

// ---------------------------------------------------------------------------
// P @ V: o[b, q, :] = P[b, qRel, :klimit] @ V[b, :klimit, :]
//   64x64 tile, BK=32, vectorized bf16x8 loads. K-loop limit = qBase+64.
// ---------------------------------------------------------------------------
__global__ void __launch_bounds__(256) pv_kernel(
    const bf16* __restrict__ p, const bf16* __restrict__ v,
    bf16* __restrict__ o, int q0) {
  int colBase = blockIdx.x * 64;
  int qBase = q0 + blockIdx.y * 64;     // global
  int b = blockIdx.z;
  int klimit = qBase + 64;
  const bf16* P = p + ((long)b * CQ + (qBase - q0)) * Sn;
  const bf16* V = v + (long)b * Sn * Hn;

  __shared__ float As[64][33];   // [q][k]
  __shared__ float Bs[32][65];   // [k][d]
  int tid = threadIdx.x;
  int tx = tid & 15;
  int ty = tid >> 4;
  int aRow = tid >> 2;           // 0..63
  int aCol = (tid & 3) * 8;      // 0..24
  int bRow = tid >> 3;           // 0..31
  int bCol = (tid & 7) * 8;      // 0..56

  float acc[4][4] = {};

  for (int kt = 0; kt < klimit; kt += 32) {
    Pk8 pa, pb;
    pa.v = *reinterpret_cast<const float4*>(P + (long)aRow * Sn + kt + aCol);
    pb.v = *reinterpret_cast<const float4*>(V + (long)(kt + bRow) * Hn + colBase + bCol);
#pragma unroll
    for (int i = 0; i < 8; i++) As[aRow][aCol + i] = b2f(pa.h[i]);
#pragma unroll
    for (int i = 0; i < 8; i++) Bs[bRow][bCol + i] = b2f(pb.h[i]);
    __syncthreads();
#pragma unroll
    for (int dd = 0; dd < 32; dd++) {
      float a[4], bb[4];
#pragma unroll
      for (int i = 0; i < 4; i++) a[i] = As[ty * 4 + i][dd];
#pragma unroll
      for (int j = 0; j < 4; j++) bb[j] = Bs[dd][tx * 4 + j];
#pragma unroll
      for (int i = 0; i < 4; i++)
#pragma unroll
        for (int j = 0; j < 4; j++) acc[i][j] += a[i] * bb[j];
    }
    __syncthreads();
  }

#pragma unroll
  for (int i = 0; i < 4; i++) {
    long qg = qBase + ty * 4 + i;
#pragma unroll
    for (int j = 0; j < 4; j++)
      stc(o + ((long)b * Sn + qg) * Hn + colBase + tx * 4 + j, acc[i][j]);
  }
}

// ---------------------------------------------------------------------------
// Classifier head: last non-pad token per batch row, dot with cls_W. out: f32
// ---------------------------------------------------------------------------
__global__ void __launch_bounds__(256) cls_kernel(
    const bf16* __restrict__ h, const int* __restrict__ mask,
    const float* __restrict__ clsW, const float* __restrict__ clsb,
    float* __restrict__ out) {
  int b = blockIdx.x;
  int tid = threadIdx.x;
  __shared__ float sb[4];
  __shared__ int ib[4];
  __shared__ int lastsh;

  int ls = 0;
  for (int s = tid; s < Sn; s += 256) ls += mask[b * Sn + s];
#pragma unroll
  for (int off = 32; off > 0; off >>= 1) ls += __shfl_down(ls, off, 64);
  if ((tid & 63) == 0) ib[tid >> 6] = ls;
  __syncthreads();
  if (tid == 0) lastsh = ib[0] + ib[1] + ib[2] + ib[3] - 1;
  __syncthreads();
  int last = lastsh;

  const bf16* row = h + ((long)b * Sn + last) * Hn;
  float acc = 0.f;
  for (int d = tid; d < Hn; d += 256) acc += b2f(row[d]) * clsW[d];
#pragma unroll
  for (int off = 32; off > 0; off >>= 1) acc += __shfl_down(acc, off, 64);
  if ((tid & 63) == 0) sb[tid >> 6] = acc;
  __syncthreads();
  if (tid == 0) out[b] = sb[0] + sb[1] + sb[2] + sb[3] + clsb[0];
}

// ---------------------------------------------------------------------------
// Orchestration
// ---------------------------------------------------------------------------
extern "C" void kernel_launch(void* const* d_in, const int* in_sizes, int n_in,
                              void* d_out, int out_size, void* d_ws,
                              size_t ws_size, hipStream_t stream) {
  const int* ids     = (const int*)d_in[0];
  const int* mask    = (const int*)d_in[1];
  const float* tok   = (const float*)d_in[2];
  const float* pos   = (const float*)d_in[3];
  const float* Wq    = (const float*)d_in[4];
  const float* bq    = (const float*)d_in[5];
  const float* Wk    = (const float*)d_in[6];
  const float* bk    = (const float*)d_in[7];
  const float* Wv    = (const float*)d_in[8];
  const float* bv    = (const float*)d_in[9];
  const float* Wo    = (const float*)d_in[10];
  const float* bo    = (const float*)d_in[11];
  const float* ln1g  = (const float*)d_in[12];
  const float* ln1b  = (const float*)d_in[13];
  const float* ln2g  = (const float*)d_in[14];
  const float* ln2b  = (const float*)d_in[15];
  const float* W1    = (const float*)d_in[16];
  const float* b1    = (const float*)d_in[17];
  const float* W2    = (const float*)d_in[18];
  const float* b2    = (const float*)d_in[19];
  const float* flng  = (const float*)d_in[20];
  const float* flnb  = (const float*)d_in[21];
  const float* clsW  = (const float*)d_in[22];
  const float* clsb  = (const float*)d_in[23];

  // Workspace layout (~176 MB total, unchanged from passing round):
  //   x  : BS*H f32   (persistent hidden state)         50.3 MB
  //   h  : BS*H bf16  (LN output / attention output)    25.2 MB
  //   cb : BS*FF bf16 (q,k,v + score chunk during attention; FFN mid later)
  float* x = (float*)d_ws;
  bf16* h  = (bf16*)(x + (size_t)BSn * Hn);
  bf16* cb = h + (size_t)BSn * Hn;
  bf16* qb = cb;
  bf16* kb = cb + (size_t)BSn * Hn;
  bf16* vb = cb + 2 * (size_t)BSn * Hn;
  bf16* scb = cb + 3 * (size_t)BSn * Hn;  // [Bn, CQ, Sn] bf16 = 16.8 MB (< 25.2 spare)

  const int M = BSn;
  dim3 blk(256);
  dim3 gridH(Hn / 64, M / 64);    // N=768
  dim3 gridF(FFn / 64, M / 64);   // N=3072
  dim3 gridQK(Sn / 64, CQ / 64, Bn);
  dim3 gridSM(CQ, Bn);
  dim3 gridPV(Hn / 64, CQ / 64, Bn);

  embed_kernel<<<BSn, blk, 0, stream>>>(ids, tok, pos, x);

  for (int l = 0; l < Ln; l++) {
    const float* Wq_l = Wq + (size_t)l * Hn * Hn;
    const float* Wk_l = Wk + (size_t)l * Hn * Hn;
    const float* Wv_l = Wv + (size_t)l * Hn * Hn;
    const float* Wo_l = Wo + (size_t)l * Hn * Hn;
    const float* W1_l = W1 + (size_t)l * Hn * FFn;
    const float* W2_l = W2 + (size_t)l * FFn * Hn;

    // --- attention block ---
    ln_kernel<<<BSn, blk, 0, stream>>>(x, ln1g + l * Hn, ln1b + l * Hn, h);
    gemm_kernel<0, bf16><<<gridH, blk, 0, stream>>>(h, Wq_l, bq + l * Hn,
                                                    nullptr, qb, M, Hn, Hn);
    gemm_kernel<0, bf16><<<gridH, blk, 0, stream>>>(h, Wk_l, bk + l * Hn,
                                                    nullptr, kb, M, Hn, Hn);
    gemm_kernel<0, bf16><<<gridH, blk, 0, stream>>>(h, Wv_l, bv + l * Hn,
                                                    nullptr, vb, M, Hn, Hn);
    for (int c = 0; c < Sn / CQ; c++) {
      int q0 = c * CQ;
      qk_kernel<<<gridQK, blk, 0, stream>>>(qb, kb, scb, q0);
      softmax_kernel<<<gridSM, blk, 0, stream>>>(scb, mask, q0);
      pv_kernel<<<gridPV, blk, 0, stream>>>(scb, vb, h, q0);
    }
    gemm_kernel<1, float><<<gridH, blk, 0, stream>>>(h, Wo_l, bo + l * Hn, x,
                                                     x, M, Hn, Hn);

    // --- FFN block ---
    ln_kernel<<<BSn, blk, 0, stream>>>(x, ln2g + l * Hn, ln2b + l * Hn, h);
    gemm_kernel<2, bf16><<<gridF, blk, 0, stream>>>(h, W1_l, b1 + l * FFn,
                                                    nullptr, cb, M, FFn, Hn);
    gemm_kernel<1, float><<<gridH, blk, 0, stream>>>(cb, W2_l, b2 + l * Hn, x,
                                                     x, M, Hn, FFn);
  }

  ln_kernel<<<BSn, blk, 0, stream>>>(x, flng, flnb, h);
  cls_kernel<<<Bn, blk, 0, stream>>>(h, mask, clsW, clsb, (float*)d_out);
}

// Round 5
// 12287.227 us; speedup vs baseline: 4.1744x; 2.3649x over previous
//
#include <hip/hip_runtime.h>
#include <hip/hip_bf16.h>

// Problem constants (BinaryClassifyModel: L=6, B=8, S=2048, H=768, V=32000)
// All model inputs are float32 (per reference); internal activations bf16.
#define Bn 8
#define Sn 2048
#define Hn 768
#define FFn 3072
#define Ln 6
#define BSn (Bn * Sn)       // 16384 tokens
#define CQ 512              // query chunk for attention scores buffer
#define LN_EPS 1e-5f

typedef __hip_bfloat16 bf16;
typedef __bf16 bf16x8 __attribute__((ext_vector_type(8)));
typedef float f32x4 __attribute__((ext_vector_type(4)));

__device__ __forceinline__ float b2f(bf16 v) { return __bfloat162float(v); }
__device__ __forceinline__ void stc(float* p, float v) { *p = v; }
__device__ __forceinline__ void stc(bf16* p, float v) { *p = __float2bfloat16(v); }

union Pk8 { float4 v; bf16 h[8]; };   // 8 consecutive bf16 = one 16B load

// async global->LDS, 16B per lane; LDS dest = wave-uniform base + lane*16
__device__ __forceinline__ void gld16(const bf16* g, short* l) {
  __builtin_amdgcn_global_load_lds(
      (const __attribute__((address_space(1))) unsigned int*)g,
      (__attribute__((address_space(3))) unsigned int*)l, 16, 0, 0);
}

// ---------------------------------------------------------------------------
// Embedding: x[b,s,:] = tok_emb[ids[b,s],:] + pos_emb[s,:]   (f32 in, f32 out)
// ---------------------------------------------------------------------------
__global__ void __launch_bounds__(256) embed_kernel(
    const int* __restrict__ ids, const float* __restrict__ tok,
    const float* __restrict__ pos, float* __restrict__ x) {
  long t = blockIdx.x;
  int s = (int)(t & (Sn - 1));
  long id = ids[t];
  const float* tr = tok + id * Hn;
  const float* pr = pos + (long)s * Hn;
  float* xr = x + t * Hn;
  for (int d = threadIdx.x; d < Hn; d += 256)
    xr[d] = tr[d] + pr[d];
}

// ---------------------------------------------------------------------------
// Weight transpose + cast: Wt[n][k] = (bf16)W[k][n].  W: [K][N] f32.
// 32x32 tile, 256 threads (32x8), both sides coalesced.
// ---------------------------------------------------------------------------
__global__ void __launch_bounds__(256) transpose_cvt_kernel(
    const float* __restrict__ W, bf16* __restrict__ Wt, int K, int N) {
  __shared__ float t[32][33];
  int n0 = blockIdx.x * 32, k0 = blockIdx.y * 32;
  int tx = threadIdx.x & 31, ty = threadIdx.x >> 5;  // ty 0..7
#pragma unroll
  for (int i = 0; i < 32; i += 8)
    t[ty + i][tx] = W[(long)(k0 + ty + i) * N + n0 + tx];
  __syncthreads();
#pragma unroll
  for (int i = 0; i < 32; i += 8)
    stc(Wt + (long)(n0 + ty + i) * K + k0 + tx, t[tx][ty + i]);
}

// ---------------------------------------------------------------------------
// LayerNorm: one 256-thread block per token. x: f32 in, out: bf16
// ---------------------------------------------------------------------------
__global__ void __launch_bounds__(256) ln_kernel(
    const float* __restrict__ x, const float* __restrict__ g,
    const float* __restrict__ b, bf16* __restrict__ out) {
  long token = blockIdx.x;
  const float* xr = x + token * Hn;
  bf16* orow = out + token * Hn;
  int tid = threadIdx.x;

  float vals[3];
  float s1 = 0.f;
#pragma unroll
  for (int i = 0; i < 3; i++) {
    vals[i] = xr[tid + 256 * i];
    s1 += vals[i];
  }
  __shared__ float sb[4];
  __shared__ float stat[2];
#pragma unroll
  for (int off = 32; off > 0; off >>= 1) s1 += __shfl_down(s1, off, 64);
  if ((tid & 63) == 0) sb[tid >> 6] = s1;
  __syncthreads();
  if (tid == 0) stat[0] = (sb[0] + sb[1] + sb[2] + sb[3]) * (1.0f / Hn);
  __syncthreads();
  float mean = stat[0];

  float s2 = 0.f;
#pragma unroll
  for (int i = 0; i < 3; i++) {
    float d = vals[i] - mean;
    s2 += d * d;
  }
#pragma unroll
  for (int off = 32; off > 0; off >>= 1) s2 += __shfl_down(s2, off, 64);
  if ((tid & 63) == 0) sb[tid >> 6] = s2;
  __syncthreads();
  if (tid == 0)
    stat[1] = rsqrtf((sb[0] + sb[1] + sb[2] + sb[3]) * (1.0f / Hn) + LN_EPS);
  __syncthreads();
  float inv = stat[1];

#pragma unroll
  for (int i = 0; i < 3; i++) {
    int d = tid + 256 * i;
    stc(orow + d, (vals[i] - mean) * inv * g[d] + b[d]);
  }
}

// ---------------------------------------------------------------------------
// MFMA GEMM: C[M,N] = epilogue(A[M,K] @ Bt[N,K]^T + bias[N] (+ res[M,N]))
//   A: bf16 row-major [M][K];  Bt: bf16 row-major [N][K] (= B^T);
//   bias: f32; res: f32; C: bf16 or f32.
//   EPI: 0 = bias, 1 = bias + residual, 2 = gelu(bias)
//   128x128 tile, BK=32, 4 waves (each 64x64 = 4x4 mfma_16x16x32 tiles).
//   Staging: global_load_lds 16B/lane; frags: ds_read_b128.
//   M%128==0, N%128==0, K%32==0 assumed.
// ---------------------------------------------------------------------------
template <int EPI, typename CT>
__global__ void __launch_bounds__(256) mfma_gemm_kernel(
    const bf16* __restrict__ A, const bf16* __restrict__ Bt,
    const float* __restrict__ bias, const float* __restrict__ res,
    CT* __restrict__ C, int M, int N, int K) {
  __shared__ short As[128 * 32];   // [row][k] rows of 64B
  __shared__ short Bs[128 * 32];   // [col][k]
  int tid = threadIdx.x;
  int wave = tid >> 6, lane = tid & 63;
  int waveM = wave >> 1, waveN = wave & 1;
  int quad = lane >> 4, l16 = lane & 15;
  long rowBase = (long)blockIdx.y * 128;
  long colBase = (long)blockIdx.x * 128;
  const bf16* Ag = A + rowBase * K;
  const bf16* Bg = Bt + colBase * K;

  int srow = lane >> 2;           // 0..15 staging row within 16-row chunk
  int schunk = (lane & 3) * 8;    // 0,8,16,24 (k elements)

  f32x4 acc[4][4] = {};

  for (int kt = 0; kt < K; kt += 32) {
    // each wave stages 32 rows of A and 32 rows of B (2 x 16-row chunks)
#pragma unroll
    for (int c = 0; c < 2; c++) {
      int r0 = wave * 32 + c * 16;
      gld16(Ag + (long)(r0 + srow) * K + kt + schunk, &As[r0 * 32]);
      gld16(Bg + (long)(r0 + srow) * K + kt + schunk, &Bs[r0 * 32]);
    }
    __syncthreads();

    bf16x8 af[4], bfr[4];
#pragma unroll
    for (int t = 0; t < 4; t++)
      af[t] = *(const bf16x8*)&As[(waveM * 64 + t * 16 + l16) * 32 + quad * 8];
#pragma unroll
    for (int u = 0; u < 4; u++)
      bfr[u] = *(const bf16x8*)&Bs[(waveN * 64 + u * 16 + l16) * 32 + quad * 8];
#pragma unroll
    for (int t = 0; t < 4; t++)
#pragma unroll
      for (int u = 0; u < 4; u++)
        acc[t][u] = __builtin_amdgcn_mfma_f32_16x16x32_bf16(af[t], bfr[u],
                                                            acc[t][u], 0, 0, 0);
    __syncthreads();
  }

  // epilogue: D col=lane&15, row=quad*4+reg  [verified mapping]
#pragma unroll
  for (int t = 0; t < 4; t++) {
#pragma unroll
    for (int u = 0; u < 4; u++) {
      int col = (int)colBase + waveN * 64 + u * 16 + l16;
      float bv = bias[col];
#pragma unroll
      for (int r = 0; r < 4; r++) {
        long row = rowBase + waveM * 64 + t * 16 + quad * 4 + r;
        float v = acc[t][u][r] + bv;
        if (EPI == 1) v += res[row * N + col];
        if (EPI == 2) v = 0.5f * v * (1.0f + erff(v * 0.70710678118654752f));
        stc(C + row * N + col, v);
      }
    }
  }
}

// ---------------------------------------------------------------------------
// QK^T: sc[b, qRel, k] = scale * dot(q[b,q0+qRel,:], k[b,k,:])
// ---------------------------------------------------------------------------
__global__ void __launch_bounds__(256) qk_kernel(
    const bf16* __restrict__ q, const bf16* __restrict__ k,
    bf16* __restrict__ sc, int q0) {
  int kBase = blockIdx.x * 64;
  int qBase = q0 + blockIdx.y * 64;
  if (kBase > qBase + 63) return;       // fully masked tile
  int b = blockIdx.z;
  long base = (long)b * Sn * Hn;
  const bf16* Q = q + base;
  const bf16* K = k + base;

  __shared__ float Qs[64][33];
  __shared__ float Ks[32][65];
  int tid = threadIdx.x;
  int tx = tid & 15;
  int ty = tid >> 4;
  int row = tid >> 2;
  int dCol = (tid & 3) * 8;

  float acc[4][4] = {};

  for (int dt = 0; dt < Hn; dt += 32) {
    Pk8 pq, pk;
    pq.v = *reinterpret_cast<const float4*>(Q + (long)(qBase + row) * Hn + dt + dCol);
    pk.v = *reinterpret_cast<const float4*>(K + (long)(kBase + row) * Hn + dt + dCol);
#pragma unroll
    for (int i = 0; i < 8; i++) Qs[row][dCol + i] = b2f(pq.h[i]);
#pragma unroll
    for (int i = 0; i < 8; i++) Ks[dCol + i][row] = b2f(pk.h[i]);
    __syncthreads();
#pragma unroll
    for (int dd = 0; dd < 32; dd++) {
      float a[4], bb[4];
#pragma unroll
      for (int i = 0; i < 4; i++) a[i] = Qs[ty * 4 + i][dd];
#pragma unroll
      for (int j = 0; j < 4; j++) bb[j] = Ks[dd][tx * 4 + j];
#pragma unroll
      for (int i = 0; i < 4; i++)
#pragma unroll
        for (int j = 0; j < 4; j++) acc[i][j] += a[i] * bb[j];
    }
    __syncthreads();
  }

  const float scale = 0.03608439182435161f;  // 1/sqrt(768)
#pragma unroll
  for (int i = 0; i < 4; i++) {
    long qRel = qBase - q0 + ty * 4 + i;
#pragma unroll
    for (int j = 0; j < 4; j++)
      stc(sc + ((long)b * CQ + qRel) * Sn + kBase + tx * 4 + j,
          acc[i][j] * scale);
  }
}

// ---------------------------------------------------------------------------
// Softmax over one score row (block per (qRel, b)).
// ---------------------------------------------------------------------------
__global__ void __launch_bounds__(256) softmax_kernel(
    bf16* __restrict__ sc, const int* __restrict__ mask, int q0) {
  int qRel = blockIdx.x;
  int b = blockIdx.y;
  int qg = q0 + qRel;
  bf16* row = sc + ((long)b * CQ + qRel) * Sn;
  const int* mrow = mask + b * Sn;
  int tid = threadIdx.x;
  int n = qg + 1;
  int limit = (qg & ~63) + 64;

  float sv[8];
  float lmax = -1e30f;
#pragma unroll
  for (int it = 0; it < 8; it++) {
    int kk = tid + it * 256;
    float s = -1e30f;
    if (kk < n) {
      s = b2f(row[kk]);
      if (mrow[kk] == 0) s = -1e30f;
    }
    sv[it] = s;
    lmax = fmaxf(lmax, s);
  }
  __shared__ float sb[4];
  __shared__ float stat;
#pragma unroll
  for (int off = 32; off > 0; off >>= 1)
    lmax = fmaxf(lmax, __shfl_down(lmax, off, 64));
  if ((tid & 63) == 0) sb[tid >> 6] = lmax;
  __syncthreads();
  if (tid == 0) stat = fmaxf(fmaxf(sb[0], sb[1]), fmaxf(sb[2], sb[3]));
  __syncthreads();
  float gmax = stat;

  float ev[8];
  float lsum = 0.f;
#pragma unroll
  for (int it = 0; it < 8; it++) {
    int kk = tid + it * 256;
    float e = 0.f;
    if (kk < n) e = __expf(sv[it] - gmax);
    ev[it] = e;
    lsum += e;
  }
#pragma unroll
  for (int off = 32; off > 0; off >>= 1) lsum += __shfl_down(lsum, off, 64);
  if ((tid & 63) == 0) sb[tid >> 6] = lsum;
  __syncthreads();
  if (tid == 0) stat = sb[0] + sb[1] + sb[2] + sb[3];
  __syncthreads();
  float inv = 1.0f / stat;

#pragma unroll
  for (int it = 0; it < 8; it++) {
    int kk = tid + it * 256;
    if (kk < n)
      stc(row + kk, ev[it] * inv);
    else if (kk < limit)
      stc(row + kk, 0.f);
  }
}

// ---------------------------------------------------------------------------
// P @ V: o[b, q, :] = P[b, qRel, :klimit] @ V[b, :klimit, :]
// ---------------------------------------------------------------------------
__global__ void __launch_bounds__(256) pv_kernel(
    const bf16* __restrict__ p, const bf16* __restrict__ v,
    bf16* __restrict__ o, int q0) {
  int colBase = blockIdx.x * 64;
  int qBase = q0 + blockIdx.y * 64;
  int b = blockIdx.z;
  int klimit = qBase + 64;
  const bf16* P = p + ((long)b * CQ + (qBase - q0)) * Sn;
  const bf16* V = v + (long)b * Sn * Hn;

  __shared__ float As[64][33];
  __shared__ float Bs[32][65];
  int tid = threadIdx.x;
  int tx = tid & 15;
  int ty = tid >> 4;
  int aRow = tid >> 2;
  int aCol = (tid & 3) * 8;
  int bRow = tid >> 3;
  int bCol = (tid & 7) * 8;

  float acc[4][4] = {};

  for (int kt = 0; kt < klimit; kt += 32) {
    Pk8 pa, pb;
    pa.v = *reinterpret_cast<const float4*>(P + (long)aRow * Sn + kt + aCol);
    pb.v = *reinterpret_cast<const float4*>(V + (long)(kt + bRow) * Hn + colBase + bCol);
#pragma unroll
    for (int i = 0; i < 8; i++) As[aRow][aCol + i] = b2f(pa.h[i]);
#pragma unroll
    for (int i = 0; i < 8; i++) Bs[bRow][bCol + i] = b2f(pb.h[i]);
    __syncthreads();
#pragma unroll
    for (int dd = 0; dd < 32; dd++) {
      float a[4], bb[4];
#pragma unroll
      for (int i = 0; i < 4; i++) a[i] = As[ty * 4 + i][dd];
#pragma unroll
      for (int j = 0; j < 4; j++) bb[j] = Bs[dd][tx * 4 + j];
#pragma unroll
      for (int i = 0; i < 4; i++)
#pragma unroll
        for (int j = 0; j < 4; j++) acc[i][j] += a[i] * bb[j];
    }
    __syncthreads();
  }

#pragma unroll
  for (int i = 0; i < 4; i++) {
    long qg = qBase + ty * 4 + i;
#pragma unroll
    for (int j = 0; j < 4; j++)
      stc(o + ((long)b * Sn + qg) * Hn + colBase + tx * 4 + j, acc[i][j]);
  }
}

// ---------------------------------------------------------------------------
// Classifier head
// ---------------------------------------------------------------------------
__global__ void __launch_bounds__(256) cls_kernel(
    const bf16* __restrict__ h, const int* __restrict__ mask,
    const float* __restrict__ clsW, const float* __restrict__ clsb,
    float* __restrict__ out) {
  int b = blockIdx.x;
  int tid = threadIdx.x;
  __shared__ float sb[4];
  __shared__ int ib[4];
  __shared__ int lastsh;

  int ls = 0;
  for (int s = tid; s < Sn; s += 256) ls += mask[b * Sn + s];
#pragma unroll
  for (int off = 32; off > 0; off >>= 1) ls += __shfl_down(ls, off, 64);
  if ((tid & 63) == 0) ib[tid >> 6] = ls;
  __syncthreads();
  if (tid == 0) lastsh = ib[0] + ib[1] + ib[2] + ib[3] - 1;
  __syncthreads();
  int last = lastsh;

  const bf16* row = h + ((long)b * Sn + last) * Hn;
  float acc = 0.f;
  for (int d = tid; d < Hn; d += 256) acc += b2f(row[d]) * clsW[d];
#pragma unroll
  for (int off = 32; off > 0; off >>= 1) acc += __shfl_down(acc, off, 64);
  if ((tid & 63) == 0) sb[tid >> 6] = acc;
  __syncthreads();
  if (tid == 0) out[b] = sb[0] + sb[1] + sb[2] + sb[3] + clsb[0];
}

// ---------------------------------------------------------------------------
// Orchestration
// ---------------------------------------------------------------------------
extern "C" void kernel_launch(void* const* d_in, const int* in_sizes, int n_in,
                              void* d_out, int out_size, void* d_ws,
                              size_t ws_size, hipStream_t stream) {
  const int* ids     = (const int*)d_in[0];
  const int* mask    = (const int*)d_in[1];
  const float* tok   = (const float*)d_in[2];
  const float* pos   = (const float*)d_in[3];
  const float* Wq    = (const float*)d_in[4];
  const float* bq    = (const float*)d_in[5];
  const float* Wk    = (const float*)d_in[6];
  const float* bk    = (const float*)d_in[7];
  const float* Wv    = (const float*)d_in[8];
  const float* bv    = (const float*)d_in[9];
  const float* Wo    = (const float*)d_in[10];
  const float* bo    = (const float*)d_in[11];
  const float* ln1g  = (const float*)d_in[12];
  const float* ln1b  = (const float*)d_in[13];
  const float* ln2g  = (const float*)d_in[14];
  const float* ln2b  = (const float*)d_in[15];
  const float* W1    = (const float*)d_in[16];
  const float* b1    = (const float*)d_in[17];
  const float* W2    = (const float*)d_in[18];
  const float* b2    = (const float*)d_in[19];
  const float* flng  = (const float*)d_in[20];
  const float* flnb  = (const float*)d_in[21];
  const float* clsW  = (const float*)d_in[22];
  const float* clsb  = (const float*)d_in[23];

  // Workspace layout (~190 MB):
  //   x  : BS*H f32   (persistent hidden state)         50.3 MB
  //   h  : BS*H bf16  (LN output / attention output)    25.2 MB
  //   cb : BS*FF bf16 (q,k,v + scores chunk; FFN mid)  100.7 MB
  //   wt : per-layer transposed bf16 weights            14.2 MB
  float* x = (float*)d_ws;
  bf16* h  = (bf16*)(x + (size_t)BSn * Hn);
  bf16* cb = h + (size_t)BSn * Hn;
  bf16* qb = cb;
  bf16* kb = cb + (size_t)BSn * Hn;
  bf16* vb = cb + 2 * (size_t)BSn * Hn;
  bf16* scb = cb + 3 * (size_t)BSn * Hn;  // [Bn, CQ, Sn] bf16 = 16.8 MB
  bf16* wt = cb + (size_t)BSn * FFn;
  bf16* wqT = wt;                                   // [H][H]
  bf16* wkT = wqT + (size_t)Hn * Hn;
  bf16* wvT = wkT + (size_t)Hn * Hn;
  bf16* woT = wvT + (size_t)Hn * Hn;
  bf16* w1T = woT + (size_t)Hn * Hn;                // [FF][H]
  bf16* w2T = w1T + (size_t)Hn * FFn;               // [H][FF]

  const int M = BSn;
  dim3 blk(256);
  dim3 gridH128(Hn / 128, M / 128);   // N=768
  dim3 gridF128(FFn / 128, M / 128);  // N=3072
  dim3 gridQK(Sn / 64, CQ / 64, Bn);
  dim3 gridSM(CQ, Bn);
  dim3 gridPV(Hn / 64, CQ / 64, Bn);
  dim3 gridTH(Hn / 32, Hn / 32);      // transpose H x H
  dim3 gridT1(FFn / 32, Hn / 32);     // W1: K=H, N=FF
  dim3 gridT2(Hn / 32, FFn / 32);     // W2: K=FF, N=H

  embed_kernel<<<BSn, blk, 0, stream>>>(ids, tok, pos, x);

  for (int l = 0; l < Ln; l++) {
    const float* Wq_l = Wq + (size_t)l * Hn * Hn;
    const float* Wk_l = Wk + (size_t)l * Hn * Hn;
    const float* Wv_l = Wv + (size_t)l * Hn * Hn;
    const float* Wo_l = Wo + (size_t)l * Hn * Hn;
    const float* W1_l = W1 + (size_t)l * Hn * FFn;
    const float* W2_l = W2 + (size_t)l * FFn * Hn;

    // per-layer weight transpose+cast into wt (reused each layer)
    transpose_cvt_kernel<<<gridTH, blk, 0, stream>>>(Wq_l, wqT, Hn, Hn);
    transpose_cvt_kernel<<<gridTH, blk, 0, stream>>>(Wk_l, wkT, Hn, Hn);
    transpose_cvt_kernel<<<gridTH, blk, 0, stream>>>(Wv_l, wvT, Hn, Hn);
    transpose_cvt_kernel<<<gridTH, blk, 0, stream>>>(Wo_l, woT, Hn, Hn);
    transpose_cvt_kernel<<<gridT1, blk, 0, stream>>>(W1_l, w1T, Hn, FFn);
    transpose_cvt_kernel<<<gridT2, blk, 0, stream>>>(W2_l, w2T, FFn, Hn);

    // --- attention block ---
    ln_kernel<<<BSn, blk, 0, stream>>>(x, ln1g + l * Hn, ln1b + l * Hn, h);
    mfma_gemm_kernel<0, bf16><<<gridH128, blk, 0, stream>>>(
        h, wqT, bq + l * Hn, nullptr, qb, M, Hn, Hn);
    mfma_gemm_kernel<0, bf16><<<gridH128, blk, 0, stream>>>(
        h, wkT, bk + l * Hn, nullptr, kb, M, Hn, Hn);
    mfma_gemm_kernel<0, bf16><<<gridH128, blk, 0, stream>>>(
        h, wvT, bv + l * Hn, nullptr, vb, M, Hn, Hn);
    for (int c = 0; c < Sn / CQ; c++) {
      int q0 = c * CQ;
      qk_kernel<<<gridQK, blk, 0, stream>>>(qb, kb, scb, q0);
      softmax_kernel<<<gridSM, blk, 0, stream>>>(scb, mask, q0);
      pv_kernel<<<gridPV, blk, 0, stream>>>(scb, vb, h, q0);
    }
    mfma_gemm_kernel<1, float><<<gridH128, blk, 0, stream>>>(
        h, woT, bo + l * Hn, x, x, M, Hn, Hn);

    // --- FFN block ---
    ln_kernel<<<BSn, blk, 0, stream>>>(x, ln2g + l * Hn, ln2b + l * Hn, h);
    mfma_gemm_kernel<2, bf16><<<gridF128, blk, 0, stream>>>(
        h, w1T, b1 + l * FFn, nullptr, cb, M, FFn, Hn);
    mfma_gemm_kernel<1, float><<<gridH128, blk, 0, stream>>>(
        cb, w2T, b2 + l * Hn, x, x, M, Hn, FFn);
  }

  ln_kernel<<<BSn, blk, 0, stream>>>(x, flng, flnb, h);
  cls_kernel<<<Bn, blk, 0, stream>>>(h, mask, clsW, clsb, (float*)d_out);
}